// Round 1
// baseline (825.234 us; speedup 1.0000x reference)
//
#include <hip/hip_runtime.h>
#include <hip/hip_bf16.h>

typedef unsigned short u16;
typedef __attribute__((ext_vector_type(8))) short bf16x8;
typedef __attribute__((ext_vector_type(4))) short bf16x4;
typedef __attribute__((ext_vector_type(4))) float f32x4;

#define LOG2E_OVER8 0.18033688011112043f

__device__ __forceinline__ u16 f2bf(float f) {
    unsigned u = __float_as_uint(f);
    u += 0x7FFFu + ((u >> 16) & 1u);   // RNE
    return (u16)(u >> 16);
}

__device__ __forceinline__ f32x4 mfma32(bf16x8 a, bf16x8 b, f32x4 c) {
    return __builtin_amdgcn_mfma_f32_16x16x32_bf16(a, b, c, 0, 0, 0);
}
__device__ __forceinline__ f32x4 mfma16(bf16x4 a, bf16x4 b, f32x4 c) {
    return __builtin_amdgcn_mfma_f32_16x16x16bf16_1k(a, b, c, 0, 0, 0);
}

__device__ __forceinline__ void gload16(const void* g, void* l) {
    __builtin_amdgcn_global_load_lds((const __attribute__((address_space(1))) unsigned int*)g,
                                     (__attribute__((address_space(3))) unsigned int*)l,
                                     16, 0, 0);
}

// ---------------- fp32 -> bf16 conversion (vectorized x4) ----------------
__global__ __launch_bounds__(256) void cvt_bf16(const float* __restrict__ in, u16* __restrict__ out) {
    size_t i = ((size_t)blockIdx.x * 256 + threadIdx.x) * 4;
    float4 v = *(const float4*)(in + i);
    u16 r0 = f2bf(v.x), r1 = f2bf(v.y), r2 = f2bf(v.z), r3 = f2bf(v.w);
    bf16x4 o; o[0] = (short)r0; o[1] = (short)r1; o[2] = (short)r2; o[3] = (short)r3;
    *(bf16x4*)(out + i) = o;
}

// ---------------- GEMM: C[m,n] = sum_k A[m,k] * Bt[n,k] + bias[n] ----------------
// M=8192, N=1024, K=1024 fixed. 128x128 tile, BK=32, 4 waves, 4x4 16x16 accs/wave.
// MODE 0: fp32 out [m*N+n]. MODE 1: bf16 out [(m*N+n)], value=(acc+bias)*scale.
// MODE 2: bf16 out transposed per-head: VT[((m>>11)*1024 + n)*2048 + (m&2047)].
template<int MODE>
__global__ __launch_bounds__(256) void gemm_bt(const u16* __restrict__ A, const u16* __restrict__ Bt,
                                               const float* __restrict__ bias, void* __restrict__ Cout,
                                               float scale) {
    constexpr int K = 1024, N = 1024;
    __shared__ u16 As[128 * 32];
    __shared__ u16 Bs[128 * 32];
    const int tid = threadIdx.x;
    const int lane = tid & 63, wid = tid >> 6;
    const int wr = wid >> 1, wc = wid & 1;
    const int lr = lane & 15, lg = lane >> 4;
    const int bm = blockIdx.y * 128, bn = blockIdx.x * 128;

    f32x4 acc[4][4];
    for (int i = 0; i < 4; i++)
        for (int j = 0; j < 4; j++) acc[i][j] = (f32x4){0.f, 0.f, 0.f, 0.f};

    const int c0 = tid, c1 = 256 + tid;
    const size_t a_off0 = (size_t)(bm + (c0 >> 2)) * K + (c0 & 3) * 8;
    const size_t a_off1 = (size_t)(bm + (c1 >> 2)) * K + (c1 & 3) * 8;
    const size_t b_off0 = (size_t)(bn + (c0 >> 2)) * K + (c0 & 3) * 8;
    const size_t b_off1 = (size_t)(bn + (c1 >> 2)) * K + (c1 & 3) * 8;

    for (int kt = 0; kt < K; kt += 32) {
        gload16(A + a_off0 + kt, &As[c0 * 8]);
        gload16(A + a_off1 + kt, &As[c1 * 8]);
        gload16(Bt + b_off0 + kt, &Bs[c0 * 8]);
        gload16(Bt + b_off1 + kt, &Bs[c1 * 8]);
        __syncthreads();
        bf16x8 aF[4], bF[4];
#pragma unroll
        for (int mi = 0; mi < 4; mi++) aF[mi] = *(const bf16x8*)&As[(wr * 64 + mi * 16 + lr) * 32 + lg * 8];
#pragma unroll
        for (int ni = 0; ni < 4; ni++) bF[ni] = *(const bf16x8*)&Bs[(wc * 64 + ni * 16 + lr) * 32 + lg * 8];
#pragma unroll
        for (int mi = 0; mi < 4; mi++)
#pragma unroll
            for (int ni = 0; ni < 4; ni++) acc[mi][ni] = mfma32(aF[mi], bF[ni], acc[mi][ni]);
        __syncthreads();
    }

#pragma unroll
    for (int ni = 0; ni < 4; ni++) {
        const int n = bn + wc * 64 + ni * 16 + lr;
        const float bv = bias[n];
#pragma unroll
        for (int mi = 0; mi < 4; mi++) {
            const int mbase = bm + wr * 64 + mi * 16 + lg * 4;
#pragma unroll
            for (int r = 0; r < 4; r++) {
                const int m = mbase + r;
                const float v = acc[mi][ni][r] + bv;
                if (MODE == 0) {
                    ((float*)Cout)[(size_t)m * N + n] = v;
                } else if (MODE == 1) {
                    ((u16*)Cout)[(size_t)m * N + n] = f2bf(v * scale);
                } else {
                    ((u16*)Cout)[((size_t)((m >> 11) * 1024 + n)) * 2048 + (m & 2047)] = f2bf(v);
                }
            }
        }
    }
}

// ---------------- Flash attention ----------------
// Qp, Kp: bf16 [B*S, 1024] (head h at cols h*64..h*64+63); Qp pre-scaled by log2e/8.
// VT: bf16 [B,H,64,2048]. AO out: bf16 [B*S, 1024] merged heads.
// Grid: (S/64, B*H), 4 waves/block, each wave owns 16 q rows.
// Swapped QK^T: scores tile = mfma(K_frag, Q_frag) -> D[k_row, q_col]; the
// exp()'d tile is then directly a 16x16x16 B-operand for PV (zero shuffles).
__global__ __launch_bounds__(256) void attn_fwd(const u16* __restrict__ Qp, const u16* __restrict__ Kp,
                                                const u16* __restrict__ VTb, u16* __restrict__ AO) {
    const int lane = threadIdx.x & 63, wave = threadIdx.x >> 6;
    const int lr = lane & 15, lg = lane >> 4;
    const int bh = blockIdx.y, b = bh >> 4, h = bh & 15;
    const int q0 = blockIdx.x * 64 + wave * 16;

    const u16* qrow = Qp + (size_t)(b * 2048 + q0 + lr) * 1024 + h * 64;
    const bf16x8 qf0 = *(const bf16x8*)(qrow + lg * 8);
    const bf16x8 qf1 = *(const bf16x8*)(qrow + 32 + lg * 8);

    const u16* Kb = Kp + (size_t)(b * 2048) * 1024 + h * 64 + (size_t)lr * 1024 + lg * 8;
    const u16* Vb = VTb + (size_t)(b * 16 + h) * 64 * 2048 + (size_t)lr * 2048 + lg * 4;

    float mrow = -3.0e38f, lsum = 0.f;
    f32x4 ot[4];
    for (int i = 0; i < 4; i++) ot[i] = (f32x4){0.f, 0.f, 0.f, 0.f};

    for (int k0 = 0; k0 < 2048; k0 += 32) {
        const u16* kp0 = Kb + (size_t)k0 * 1024;
        const u16* kp1 = kp0 + 16 * 1024;
        bf16x8 ka0 = *(const bf16x8*)(kp0);
        bf16x8 ka1 = *(const bf16x8*)(kp0 + 32);
        bf16x8 kb0 = *(const bf16x8*)(kp1);
        bf16x8 kb1 = *(const bf16x8*)(kp1 + 32);
        f32x4 s0 = (f32x4){0.f, 0.f, 0.f, 0.f}, s1 = (f32x4){0.f, 0.f, 0.f, 0.f};
        s0 = mfma32(ka0, qf0, s0);
        s0 = mfma32(ka1, qf1, s0);
        s1 = mfma32(kb0, qf0, s1);
        s1 = mfma32(kb1, qf1, s1);
        // scores are in log2 units (Q pre-scaled). Row(q) reduce across lane groups.
        float t = fmaxf(fmaxf(fmaxf(s0[0], s0[1]), fmaxf(s0[2], s0[3])),
                        fmaxf(fmaxf(s1[0], s1[1]), fmaxf(s1[2], s1[3])));
        t = fmaxf(t, __shfl_xor(t, 16));
        t = fmaxf(t, __shfl_xor(t, 32));
        const float newm = fmaxf(mrow, t);
        const float sc = exp2f(mrow - newm);
        float p0[4], p1[4], psum = 0.f;
#pragma unroll
        for (int r = 0; r < 4; r++) {
            p0[r] = exp2f(s0[r] - newm);
            p1[r] = exp2f(s1[r] - newm);
            psum += p0[r] + p1[r];
        }
        psum += __shfl_xor(psum, 16);
        psum += __shfl_xor(psum, 32);
        lsum = lsum * sc + psum;
        mrow = newm;
        bf16x4 pf0, pf1;
#pragma unroll
        for (int r = 0; r < 4; r++) {
            pf0[r] = (short)f2bf(p0[r]);
            pf1[r] = (short)f2bf(p1[r]);
        }
#pragma unroll
        for (int dt = 0; dt < 4; dt++) {
            ot[dt][0] *= sc; ot[dt][1] *= sc; ot[dt][2] *= sc; ot[dt][3] *= sc;
        }
#pragma unroll
        for (int dt = 0; dt < 4; dt++) {
            const u16* vp = Vb + (size_t)(dt * 16) * 2048 + k0;
            bf16x4 v0 = *(const bf16x4*)(vp);
            bf16x4 v1 = *(const bf16x4*)(vp + 16);
            ot[dt] = mfma16(v0, pf0, ot[dt]);
            ot[dt] = mfma16(v1, pf1, ot[dt]);
        }
    }
    const float inv = 1.0f / lsum;

    // LDS transpose for coalesced merged-layout store.
    __shared__ u16 tl[4][16 * 64];
    u16* t_ = tl[wave];
#pragma unroll
    for (int dt = 0; dt < 4; dt++)
#pragma unroll
        for (int r = 0; r < 4; r++) t_[lr * 64 + dt * 16 + lg * 4 + r] = f2bf(ot[dt][r] * inv);
    __syncthreads();
    const int qq = lane >> 2, dseg = (lane & 3) * 16;
    bf16x8 o0 = *(const bf16x8*)&t_[qq * 64 + dseg];
    bf16x8 o1 = *(const bf16x8*)&t_[qq * 64 + dseg + 8];
    u16* dst = AO + (size_t)(b * 2048 + q0 + qq) * 1024 + h * 64 + dseg;
    *(bf16x8*)dst = o0;
    *(bf16x8*)(dst + 8) = o1;
}

// ---------------- launcher ----------------
extern "C" void kernel_launch(void* const* d_in, const int* in_sizes, int n_in,
                              void* d_out, int out_size, void* d_ws, size_t ws_size,
                              hipStream_t stream) {
    const float* q_in = (const float*)d_in[0];
    const float* k_in = (const float*)d_in[1];
    const float* v_in = (const float*)d_in[2];
    const float* Wq = (const float*)d_in[3];
    const float* bq = (const float*)d_in[4];
    const float* Wk = (const float*)d_in[5];
    const float* bk = (const float*)d_in[6];
    const float* Wv = (const float*)d_in[7];
    const float* bv = (const float*)d_in[8];
    const float* Wo = (const float*)d_in[9];
    const float* bo = (const float*)d_in[10];

    const size_t MD = (size_t)8192 * 1024;
    const size_t DD = (size_t)1024 * 1024;
    u16* ws = (u16*)d_ws;
    u16* Xq = ws;
    u16* Xk = Xq + MD;
    u16* Xv = Xk + MD;
    u16* Wqb = Xv + MD;
    u16* Wkb = Wqb + DD;
    u16* Wvb = Wkb + DD;
    u16* Wob = Wvb + DD;
    u16* Qp = Wob + DD;
    u16* Kp = Qp + MD;
    u16* VTb = Kp + MD;
    u16* AO = VTb + MD;

    cvt_bf16<<<8192, 256, 0, stream>>>(q_in, Xq);
    cvt_bf16<<<8192, 256, 0, stream>>>(k_in, Xk);
    cvt_bf16<<<8192, 256, 0, stream>>>(v_in, Xv);
    cvt_bf16<<<1024, 256, 0, stream>>>(Wq, Wqb);
    cvt_bf16<<<1024, 256, 0, stream>>>(Wk, Wkb);
    cvt_bf16<<<1024, 256, 0, stream>>>(Wv, Wvb);
    cvt_bf16<<<1024, 256, 0, stream>>>(Wo, Wob);

    dim3 gg(8, 64);
    gemm_bt<1><<<gg, 256, 0, stream>>>(Xq, Wqb, bq, Qp, LOG2E_OVER8);
    gemm_bt<1><<<gg, 256, 0, stream>>>(Xk, Wkb, bk, Kp, 1.0f);
    gemm_bt<2><<<gg, 256, 0, stream>>>(Xv, Wvb, bv, VTb, 1.0f);

    attn_fwd<<<dim3(32, 64), 256, 0, stream>>>(Qp, Kp, VTb, AO);

    gemm_bt<0><<<gg, 256, 0, stream>>>(AO, Wob, bo, d_out, 1.0f);
}

// Round 2
// 340.992 us; speedup vs baseline: 2.4201x; 2.4201x over previous
//
#include <hip/hip_runtime.h>
#include <hip/hip_bf16.h>

typedef unsigned short u16;
typedef __attribute__((ext_vector_type(8))) short bf16x8;
typedef __attribute__((ext_vector_type(4))) short bf16x4;
typedef __attribute__((ext_vector_type(4))) float f32x4;

#define LOG2E_OVER8 0.18033688011112043f

__device__ __forceinline__ u16 f2bf(float f) {
    unsigned u = __float_as_uint(f);
    u += 0x7FFFu + ((u >> 16) & 1u);   // RNE
    return (u16)(u >> 16);
}

__device__ __forceinline__ f32x4 mfma32(bf16x8 a, bf16x8 b, f32x4 c) {
    return __builtin_amdgcn_mfma_f32_16x16x32_bf16(a, b, c, 0, 0, 0);
}
__device__ __forceinline__ f32x4 mfma16(bf16x4 a, bf16x4 b, f32x4 c) {
    return __builtin_amdgcn_mfma_f32_16x16x16bf16_1k(a, b, c, 0, 0, 0);
}

__device__ __forceinline__ void gload16(const void* g, void* l) {
    __builtin_amdgcn_global_load_lds((const __attribute__((address_space(1))) unsigned int*)g,
                                     (__attribute__((address_space(3))) unsigned int*)l,
                                     16, 0, 0);
}

// ---------------- fp32 -> bf16 conversion (vectorized x4) ----------------
__global__ __launch_bounds__(256) void cvt_bf16(const float* __restrict__ in, u16* __restrict__ out) {
    size_t i = ((size_t)blockIdx.x * 256 + threadIdx.x) * 4;
    float4 v = *(const float4*)(in + i);
    u16 r0 = f2bf(v.x), r1 = f2bf(v.y), r2 = f2bf(v.z), r3 = f2bf(v.w);
    bf16x4 o; o[0] = (short)r0; o[1] = (short)r1; o[2] = (short)r2; o[3] = (short)r3;
    *(bf16x4*)(out + i) = o;
}

// ---------------- GEMM: C[m,n] = sum_k A[m,k] * Bt[n,k] + bias[n] ----------------
template<int MODE>
__global__ __launch_bounds__(256) void gemm_bt(const u16* __restrict__ A, const u16* __restrict__ Bt,
                                               const float* __restrict__ bias, void* __restrict__ Cout,
                                               float scale) {
    constexpr int K = 1024, N = 1024;
    __shared__ u16 As[128 * 32];
    __shared__ u16 Bs[128 * 32];
    const int tid = threadIdx.x;
    const int lane = tid & 63, wid = tid >> 6;
    const int wr = wid >> 1, wc = wid & 1;
    const int lr = lane & 15, lg = lane >> 4;
    const int bm = blockIdx.y * 128, bn = blockIdx.x * 128;

    f32x4 acc[4][4];
    for (int i = 0; i < 4; i++)
        for (int j = 0; j < 4; j++) acc[i][j] = (f32x4){0.f, 0.f, 0.f, 0.f};

    const int c0 = tid, c1 = 256 + tid;
    const size_t a_off0 = (size_t)(bm + (c0 >> 2)) * K + (c0 & 3) * 8;
    const size_t a_off1 = (size_t)(bm + (c1 >> 2)) * K + (c1 & 3) * 8;
    const size_t b_off0 = (size_t)(bn + (c0 >> 2)) * K + (c0 & 3) * 8;
    const size_t b_off1 = (size_t)(bn + (c1 >> 2)) * K + (c1 & 3) * 8;

    for (int kt = 0; kt < K; kt += 32) {
        gload16(A + a_off0 + kt, &As[c0 * 8]);
        gload16(A + a_off1 + kt, &As[c1 * 8]);
        gload16(Bt + b_off0 + kt, &Bs[c0 * 8]);
        gload16(Bt + b_off1 + kt, &Bs[c1 * 8]);
        __syncthreads();
        bf16x8 aF[4], bF[4];
#pragma unroll
        for (int mi = 0; mi < 4; mi++) aF[mi] = *(const bf16x8*)&As[(wr * 64 + mi * 16 + lr) * 32 + lg * 8];
#pragma unroll
        for (int ni = 0; ni < 4; ni++) bF[ni] = *(const bf16x8*)&Bs[(wc * 64 + ni * 16 + lr) * 32 + lg * 8];
#pragma unroll
        for (int mi = 0; mi < 4; mi++)
#pragma unroll
            for (int ni = 0; ni < 4; ni++) acc[mi][ni] = mfma32(aF[mi], bF[ni], acc[mi][ni]);
        __syncthreads();
    }

#pragma unroll
    for (int ni = 0; ni < 4; ni++) {
        const int n = bn + wc * 64 + ni * 16 + lr;
        const float bv = bias[n];
#pragma unroll
        for (int mi = 0; mi < 4; mi++) {
            const int mbase = bm + wr * 64 + mi * 16 + lg * 4;
#pragma unroll
            for (int r = 0; r < 4; r++) {
                const int m = mbase + r;
                const float v = acc[mi][ni][r] + bv;
                if (MODE == 0) {
                    ((float*)Cout)[(size_t)m * N + n] = v;
                } else if (MODE == 1) {
                    ((u16*)Cout)[(size_t)m * N + n] = f2bf(v * scale);
                } else {
                    ((u16*)Cout)[((size_t)((m >> 11) * 1024 + n)) * 2048 + (m & 2047)] = f2bf(v);
                }
            }
        }
    }
}

// ---------------- Flash attention v2: LDS-staged K/V, double-buffered ----------------
// Qp, Kp: bf16 [B*S, 1024]; Qp pre-scaled by log2e/8. VT: bf16 [B,H,64,2048].
// Grid: (S/128, B*H), 4 waves/block; each wave owns 32 q rows (2 q-tiles of 16).
// KVBLK=64 per iter; K tile [64k][64d], V tile [64d][64k], both XOR-swizzled
// (16B granularity, row&7) via pre-swizzled global source + swizzled ds_read.
__global__ __launch_bounds__(256) void attn_fwd(const u16* __restrict__ Qp, const u16* __restrict__ Kp,
                                                const u16* __restrict__ VTb, u16* __restrict__ AO) {
    __shared__ u16 kt[2][4096];   // 2 x 8KB
    __shared__ u16 vt[2][4096];   // 2 x 8KB
    const int tid = threadIdx.x;
    const int lane = tid & 63, wave = tid >> 6;
    const int lr = lane & 15, lg = lane >> 4;
    const int l7 = lr & 7;
    const int bh = blockIdx.y, b = bh >> 4, h = bh & 15;
    const int q0 = blockIdx.x * 128 + wave * 32;

    // Q fragments: qf[qt][hf], B-operand layout (lane holds Q[q0+qt*16+lr][hf*32+lg*8 ..+8))
    const u16* qbase = Qp + (size_t)(b * 2048 + q0) * 1024 + h * 64;
    bf16x8 qf[2][2];
#pragma unroll
    for (int qt = 0; qt < 2; qt++)
#pragma unroll
        for (int hf = 0; hf < 2; hf++)
            qf[qt][hf] = *(const bf16x8*)(qbase + (size_t)(qt * 16 + lr) * 1024 + hf * 32 + lg * 8);

    // staging: thread covers 8 elements (16B). row = tid>>3 (+32 per issue), swizzled col.
    const int srow = tid >> 3;
    const int scol = (((tid & 7) ^ (srow & 7)) * 8);
    const u16* kg = Kp + (size_t)(b * 2048 + srow) * 1024 + h * 64 + scol;
    const u16* vg = VTb + (size_t)(b * 16 + h) * 64 * 2048 + (size_t)srow * 2048 + scol;
    const int ldst = tid * 8;   // linear LDS element offset per issue

#define STAGE(buf, k0n)                                                     \
    do {                                                                    \
        gload16(kg + (size_t)(k0n) * 1024,        &kt[buf][ldst]);          \
        gload16(kg + (size_t)((k0n) + 32) * 1024, &kt[buf][2048 + ldst]);   \
        gload16(vg + (k0n),                       &vt[buf][ldst]);          \
        gload16(vg + 32 * 2048 + (k0n),           &vt[buf][2048 + ldst]);   \
    } while (0)

    float mrow[2] = {-3.0e38f, -3.0e38f};
    float lsum[2] = {0.f, 0.f};
    f32x4 ot[2][4];
#pragma unroll
    for (int qt = 0; qt < 2; qt++)
#pragma unroll
        for (int dt = 0; dt < 4; dt++) ot[qt][dt] = (f32x4){0.f, 0.f, 0.f, 0.f};

    STAGE(0, 0);
    __syncthreads();
    int cur = 0;

    const f32x4 zero = (f32x4){0.f, 0.f, 0.f, 0.f};
    // K-frag swizzled column units (8-elem units within 64-elem row)
    const int ku0 = (lg ^ l7) * 8;        // hf=0
    const int ku1 = ((4 + lg) ^ l7) * 8;  // hf=1

    for (int it = 0; it < 32; ++it) {
        if (it < 31) STAGE(cur ^ 1, (it + 1) * 64);

        const u16* kl = &kt[cur][0];
        const u16* vl = &vt[cur][0];

        // ---- QK^T (swapped): s[qt][ks] = K_tile x Q -> D[k_row, q_col] ----
        f32x4 s[2][4];
#pragma unroll
        for (int ks = 0; ks < 4; ++ks) {
            const int rbase = (ks * 16 + lr) * 64;
            bf16x8 kf0 = *(const bf16x8*)&kl[rbase + ku0];
            bf16x8 kf1 = *(const bf16x8*)&kl[rbase + ku1];
            s[0][ks] = mfma32(kf0, qf[0][0], zero);
            s[0][ks] = mfma32(kf1, qf[0][1], s[0][ks]);
            s[1][ks] = mfma32(kf0, qf[1][0], zero);
            s[1][ks] = mfma32(kf1, qf[1][1], s[1][ks]);
        }

        // ---- online softmax (scores already in log2 units) ----
        bf16x4 pf[2][4];
        float sc[2];
#pragma unroll
        for (int qt = 0; qt < 2; ++qt) {
            float t01 = fmaxf(fmaxf(s[qt][0][0], s[qt][0][1]), fmaxf(s[qt][0][2], s[qt][0][3]));
            float t23 = fmaxf(fmaxf(s[qt][1][0], s[qt][1][1]), fmaxf(s[qt][1][2], s[qt][1][3]));
            float t45 = fmaxf(fmaxf(s[qt][2][0], s[qt][2][1]), fmaxf(s[qt][2][2], s[qt][2][3]));
            float t67 = fmaxf(fmaxf(s[qt][3][0], s[qt][3][1]), fmaxf(s[qt][3][2], s[qt][3][3]));
            float t = fmaxf(fmaxf(t01, t23), fmaxf(t45, t67));
            t = fmaxf(t, __shfl_xor(t, 16));
            t = fmaxf(t, __shfl_xor(t, 32));
            const float newm = fmaxf(mrow[qt], t);
            sc[qt] = exp2f(mrow[qt] - newm);
            mrow[qt] = newm;
            float psum = 0.f;
#pragma unroll
            for (int ks = 0; ks < 4; ++ks) {
#pragma unroll
                for (int r = 0; r < 4; ++r) {
                    const float p = exp2f(s[qt][ks][r] - newm);
                    s[qt][ks][r] = p;
                    psum += p;
                }
                bf16x4 pk;
                pk[0] = (short)f2bf(s[qt][ks][0]);
                pk[1] = (short)f2bf(s[qt][ks][1]);
                pk[2] = (short)f2bf(s[qt][ks][2]);
                pk[3] = (short)f2bf(s[qt][ks][3]);
                pf[qt][ks] = pk;
            }
            psum += __shfl_xor(psum, 16);
            psum += __shfl_xor(psum, 32);
            lsum[qt] = lsum[qt] * sc[qt] + psum;
        }

        // ---- rescale accumulators ----
#pragma unroll
        for (int qt = 0; qt < 2; ++qt)
#pragma unroll
            for (int dt = 0; dt < 4; ++dt) {
                ot[qt][dt][0] *= sc[qt]; ot[qt][dt][1] *= sc[qt];
                ot[qt][dt][2] *= sc[qt]; ot[qt][dt][3] *= sc[qt];
            }

        // ---- PV: out^T[d, q] += VT_tile x P ----
#pragma unroll
        for (int dt = 0; dt < 4; ++dt) {
            const int vrow = (dt * 16 + lr) * 64;
            bf16x4 vf[4];
#pragma unroll
            for (int ks = 0; ks < 4; ++ks) {
                const int c = (ks * 16 + lg * 4) ^ (l7 * 8);
                vf[ks] = *(const bf16x4*)&vl[vrow + c];
            }
#pragma unroll
            for (int ks = 0; ks < 4; ++ks) {
                ot[0][dt] = mfma16(vf[ks], pf[0][ks], ot[0][dt]);
                ot[1][dt] = mfma16(vf[ks], pf[1][ks], ot[1][dt]);
            }
        }

        __syncthreads();   // drains gload_lds (stage t+1 complete) + all waves done reading cur
        cur ^= 1;
    }

    // ---- epilogue: normalize, LDS transpose, coalesced store ----
    const float inv0 = 1.0f / lsum[0], inv1 = 1.0f / lsum[1];
    u16* t_ = &kt[0][0] + wave * 2048;   // 4KB per wave (reuses staging LDS)
#pragma unroll
    for (int qt = 0; qt < 2; ++qt) {
        const float inv = qt ? inv1 : inv0;
#pragma unroll
        for (int dt = 0; dt < 4; ++dt)
#pragma unroll
            for (int r = 0; r < 4; ++r)
                t_[(qt * 16 + lr) * 64 + dt * 16 + lg * 4 + r] = f2bf(ot[qt][dt][r] * inv);
    }
    __syncthreads();
    const int qq = lane >> 1, dseg = (lane & 1) * 32;
    u16* dst = AO + (size_t)(b * 2048 + q0 + qq) * 1024 + h * 64 + dseg;
    bf16x8 o_[4];
#pragma unroll
    for (int j = 0; j < 4; ++j) o_[j] = *(const bf16x8*)&t_[qq * 64 + dseg + j * 8];
#pragma unroll
    for (int j = 0; j < 4; ++j) *(bf16x8*)(dst + j * 8) = o_[j];
#undef STAGE
}

// ---------------- launcher ----------------
extern "C" void kernel_launch(void* const* d_in, const int* in_sizes, int n_in,
                              void* d_out, int out_size, void* d_ws, size_t ws_size,
                              hipStream_t stream) {
    const float* q_in = (const float*)d_in[0];
    const float* k_in = (const float*)d_in[1];
    const float* v_in = (const float*)d_in[2];
    const float* Wq = (const float*)d_in[3];
    const float* bq = (const float*)d_in[4];
    const float* Wk = (const float*)d_in[5];
    const float* bk = (const float*)d_in[6];
    const float* Wv = (const float*)d_in[7];
    const float* bv = (const float*)d_in[8];
    const float* Wo = (const float*)d_in[9];
    const float* bo = (const float*)d_in[10];

    const size_t MD = (size_t)8192 * 1024;
    const size_t DD = (size_t)1024 * 1024;
    u16* ws = (u16*)d_ws;
    u16* Xq = ws;
    u16* Xk = Xq + MD;
    u16* Xv = Xk + MD;
    u16* Wqb = Xv + MD;
    u16* Wkb = Wqb + DD;
    u16* Wvb = Wkb + DD;
    u16* Wob = Wvb + DD;
    u16* Qp = Wob + DD;
    u16* Kp = Qp + MD;
    u16* VTb = Kp + MD;
    u16* AO = VTb + MD;

    cvt_bf16<<<8192, 256, 0, stream>>>(q_in, Xq);
    cvt_bf16<<<8192, 256, 0, stream>>>(k_in, Xk);
    cvt_bf16<<<8192, 256, 0, stream>>>(v_in, Xv);
    cvt_bf16<<<1024, 256, 0, stream>>>(Wq, Wqb);
    cvt_bf16<<<1024, 256, 0, stream>>>(Wk, Wkb);
    cvt_bf16<<<1024, 256, 0, stream>>>(Wv, Wvb);
    cvt_bf16<<<1024, 256, 0, stream>>>(Wo, Wob);

    dim3 gg(8, 64);
    gemm_bt<1><<<gg, 256, 0, stream>>>(Xq, Wqb, bq, Qp, LOG2E_OVER8);
    gemm_bt<1><<<gg, 256, 0, stream>>>(Xk, Wkb, bk, Kp, 1.0f);
    gemm_bt<2><<<gg, 256, 0, stream>>>(Xv, Wvb, bv, VTb, 1.0f);

    attn_fwd<<<dim3(16, 64), 256, 0, stream>>>(Qp, Kp, VTb, AO);

    gemm_bt<0><<<gg, 256, 0, stream>>>(AO, Wob, bo, d_out, 1.0f);
}

// Round 4
// 302.585 us; speedup vs baseline: 2.7273x; 1.1269x over previous
//
#include <hip/hip_runtime.h>
#include <hip/hip_bf16.h>

typedef unsigned short u16;
typedef __attribute__((ext_vector_type(8))) short bf16x8;
typedef __attribute__((ext_vector_type(4))) short bf16x4;
typedef __attribute__((ext_vector_type(4))) float f32x4;
typedef __attribute__((ext_vector_type(2))) unsigned int u32x2;

#define LOG2E_OVER8 0.18033688011112043f

__device__ __forceinline__ u16 f2bf(float f) {
    unsigned u = __float_as_uint(f);
    u += 0x7FFFu + ((u >> 16) & 1u);   // RNE
    return (u16)(u >> 16);
}

__device__ __forceinline__ unsigned cvtpk_bf16(float a, float b) {
    float2 t; t.x = a; t.y = b;
    __hip_bfloat162 h = __float22bfloat162_rn(t);
    unsigned r;
    __builtin_memcpy(&r, &h, 4);
    return r;
}
__device__ __forceinline__ bf16x4 pack4(float a, float b, float c, float d) {
    u32x2 p; p[0] = cvtpk_bf16(a, b); p[1] = cvtpk_bf16(c, d);
    bf16x4 r;
    __builtin_memcpy(&r, &p, 8);
    return r;
}

__device__ __forceinline__ f32x4 mfma32(bf16x8 a, bf16x8 b, f32x4 c) {
    return __builtin_amdgcn_mfma_f32_16x16x32_bf16(a, b, c, 0, 0, 0);
}
__device__ __forceinline__ f32x4 mfma16(bf16x4 a, bf16x4 b, f32x4 c) {
    return __builtin_amdgcn_mfma_f32_16x16x16bf16_1k(a, b, c, 0, 0, 0);
}

__device__ __forceinline__ void gload16(const void* g, void* l) {
    __builtin_amdgcn_global_load_lds((const __attribute__((address_space(1))) unsigned int*)g,
                                     (__attribute__((address_space(3))) unsigned int*)l,
                                     16, 0, 0);
}

// ---------------- fp32 -> bf16 conversion (vectorized x4) ----------------
__global__ __launch_bounds__(256) void cvt_bf16(const float* __restrict__ in, u16* __restrict__ out) {
    size_t i = ((size_t)blockIdx.x * 256 + threadIdx.x) * 4;
    float4 v = *(const float4*)(in + i);
    u16 r0 = f2bf(v.x), r1 = f2bf(v.y), r2 = f2bf(v.z), r3 = f2bf(v.w);
    bf16x4 o; o[0] = (short)r0; o[1] = (short)r1; o[2] = (short)r2; o[3] = (short)r3;
    *(bf16x4*)(out + i) = o;
}

// ---------------- GEMM: C[m,n] = sum_k A[m,k] * Bt[n,k] + bias[n] ----------------
// MODE 0: fp32 out. MODE 1: bf16 out, value=(acc+bias)*scale.
// MODE 2: bf16 out in attn-V "LDS image" layout:
//   [b, h, kb(32)] tiles of 4096 elems; within tile, element for (k64, d):
//   u = ((k64>>2)&3)*2 + ((k64>>5)&1); j = ((k64>>4)&1)*4 + (k64&3);
//   pos = d*64 + ((u ^ (d&7))*8) + j.
template<int MODE>
__global__ __launch_bounds__(256) void gemm_bt(const u16* __restrict__ A, const u16* __restrict__ Bt,
                                               const float* __restrict__ bias, void* __restrict__ Cout,
                                               float scale) {
    constexpr int K = 1024, N = 1024;
    __shared__ u16 As[128 * 32];
    __shared__ u16 Bs[128 * 32];
    const int tid = threadIdx.x;
    const int lane = tid & 63, wid = tid >> 6;
    const int wr = wid >> 1, wc = wid & 1;
    const int lr = lane & 15, lg = lane >> 4;
    const int bm = blockIdx.y * 128, bn = blockIdx.x * 128;

    f32x4 acc[4][4];
    for (int i = 0; i < 4; i++)
        for (int j = 0; j < 4; j++) acc[i][j] = (f32x4){0.f, 0.f, 0.f, 0.f};

    const int c0 = tid, c1 = 256 + tid;
    const size_t a_off0 = (size_t)(bm + (c0 >> 2)) * K + (c0 & 3) * 8;
    const size_t a_off1 = (size_t)(bm + (c1 >> 2)) * K + (c1 & 3) * 8;
    const size_t b_off0 = (size_t)(bn + (c0 >> 2)) * K + (c0 & 3) * 8;
    const size_t b_off1 = (size_t)(bn + (c1 >> 2)) * K + (c1 & 3) * 8;

    for (int kt = 0; kt < K; kt += 32) {
        gload16(A + a_off0 + kt, &As[c0 * 8]);
        gload16(A + a_off1 + kt, &As[c1 * 8]);
        gload16(Bt + b_off0 + kt, &Bs[c0 * 8]);
        gload16(Bt + b_off1 + kt, &Bs[c1 * 8]);
        __syncthreads();
        bf16x8 aF[4], bF[4];
#pragma unroll
        for (int mi = 0; mi < 4; mi++) aF[mi] = *(const bf16x8*)&As[(wr * 64 + mi * 16 + lr) * 32 + lg * 8];
#pragma unroll
        for (int ni = 0; ni < 4; ni++) bF[ni] = *(const bf16x8*)&Bs[(wc * 64 + ni * 16 + lr) * 32 + lg * 8];
#pragma unroll
        for (int mi = 0; mi < 4; mi++)
#pragma unroll
            for (int ni = 0; ni < 4; ni++) acc[mi][ni] = mfma32(aF[mi], bF[ni], acc[mi][ni]);
        __syncthreads();
    }

#pragma unroll
    for (int ni = 0; ni < 4; ni++) {
        const int n = bn + wc * 64 + ni * 16 + lr;
        const float bv = bias[n];
#pragma unroll
        for (int mi = 0; mi < 4; mi++) {
            const int mbase = bm + wr * 64 + mi * 16 + lg * 4;
#pragma unroll
            for (int r = 0; r < 4; r++) {
                const int m = mbase + r;
                const float v = acc[mi][ni][r] + bv;
                if (MODE == 0) {
                    ((float*)Cout)[(size_t)m * N + n] = v;
                } else if (MODE == 1) {
                    ((u16*)Cout)[(size_t)m * N + n] = f2bf(v * scale);
                } else {
                    const int bq_ = m >> 11, kk = m & 2047, kb = kk >> 6, k64 = kk & 63;
                    const int hh = n >> 6, dd = n & 63;
                    const int u = (((k64 >> 2) & 3) << 1) | ((k64 >> 5) & 1);
                    const int jj = (((k64 >> 4) & 1) << 2) | (k64 & 3);
                    ((u16*)Cout)[((size_t)((bq_ * 16 + hh) * 32 + kb)) * 4096 +
                                 dd * 64 + ((u ^ (dd & 7)) << 3) + jj] = f2bf(v);
                }
            }
        }
    }
}

// ---------------- Flash attention v3 ----------------
// Qp, Kp: bf16 [B*S, 1024]; Qp pre-scaled by log2e/8. VT: bf16 image layout (above).
// Grid: (S/128, B*H), 4 waves/block; each wave owns 32 q rows (2 q-tiles of 16).
// K tile [64k][64d] XOR-swizzled via pre-swizzled source; V tile = linear image copy.
// Softmax: defer-max (THR=8 in log2 domain), psum/lsum accumulated via ones-MFMA.
__global__ __launch_bounds__(256) void attn_fwd(const u16* __restrict__ Qp, const u16* __restrict__ Kp,
                                                const u16* __restrict__ VTb, u16* __restrict__ AO) {
    __shared__ u16 kt[2][4096];
    __shared__ u16 vt[2][4096];
    const int tid = threadIdx.x;
    const int lane = tid & 63, wave = tid >> 6;
    const int lr = lane & 15, lg = lane >> 4;
    const int l7 = lr & 7;
    const int bh = blockIdx.y, b = bh >> 4, h = bh & 15;
    const int q0 = blockIdx.x * 128 + wave * 32;

    const u16* qbase = Qp + (size_t)(b * 2048 + q0) * 1024 + h * 64;
    bf16x8 qf[2][2];
#pragma unroll
    for (int qt = 0; qt < 2; qt++)
#pragma unroll
        for (int hf = 0; hf < 2; hf++)
            qf[qt][hf] = *(const bf16x8*)(qbase + (size_t)(qt * 16 + lr) * 1024 + hf * 32 + lg * 8);

    const int srow = tid >> 3;
    const int scol = (((tid & 7) ^ (srow & 7)) * 8);
    const u16* kg = Kp + (size_t)(b * 2048 + srow) * 1024 + h * 64 + scol;
    const u16* vg = VTb + (size_t)(b * 16 + h) * 32 * 4096 + tid * 8;
    const int ldst = tid * 8;

#define STAGE(buf, kb_)                                                       \
    do {                                                                      \
        gload16(kg + (size_t)(kb_) * 64 * 1024,        &kt[buf][ldst]);       \
        gload16(kg + (size_t)((kb_) * 64 + 32) * 1024, &kt[buf][2048 + ldst]);\
        gload16(vg + (size_t)(kb_) * 4096,             &vt[buf][ldst]);       \
        gload16(vg + (size_t)(kb_) * 4096 + 2048,      &vt[buf][2048 + ldst]);\
    } while (0)

    float mrow[2] = {-3.0e38f, -3.0e38f};
    f32x4 lsacc[2];
    f32x4 ot[2][4];
#pragma unroll
    for (int qt = 0; qt < 2; qt++) {
        lsacc[qt] = (f32x4){0.f, 0.f, 0.f, 0.f};
#pragma unroll
        for (int dt = 0; dt < 4; dt++) ot[qt][dt] = (f32x4){0.f, 0.f, 0.f, 0.f};
    }

    bf16x4 ones;
    ones[0] = ones[1] = ones[2] = ones[3] = (short)0x3F80;

    STAGE(0, 0);
    __syncthreads();
    int cur = 0;

    const f32x4 zero = (f32x4){0.f, 0.f, 0.f, 0.f};
    const int ku0 = (lg ^ l7) * 8;
    const int ku1 = ((4 + lg) ^ l7) * 8;
    const int vu0 = ((lg * 2) ^ l7) * 8;
    const int vu1 = ((lg * 2 + 1) ^ l7) * 8;

    for (int it = 0; it < 32; ++it) {
        if (it < 31) STAGE(cur ^ 1, it + 1);

        const u16* kl = &kt[cur][0];
        const u16* vl = &vt[cur][0];

        // ---- QK^T (swapped): s[qt][ks] = K_tile x Q -> D[k_row, q_col] ----
        f32x4 s[2][4];
#pragma unroll
        for (int ks = 0; ks < 4; ++ks) {
            const int rbase = (ks * 16 + lr) * 64;
            bf16x8 kf0 = *(const bf16x8*)&kl[rbase + ku0];
            bf16x8 kf1 = *(const bf16x8*)&kl[rbase + ku1];
            s[0][ks] = mfma32(kf0, qf[0][0], zero);
            s[0][ks] = mfma32(kf1, qf[0][1], s[0][ks]);
            s[1][ks] = mfma32(kf0, qf[1][0], zero);
            s[1][ks] = mfma32(kf1, qf[1][1], s[1][ks]);
        }

        // ---- online softmax, defer-max, psum via ones-MFMA ----
        bf16x4 pf[2][4];
#pragma unroll
        for (int qt = 0; qt < 2; ++qt) {
            const f32x4* sq = s[qt];
            float t0 = fmaxf(fmaxf(sq[0][0], sq[0][1]), sq[0][2]);
            float t1 = fmaxf(fmaxf(sq[0][3], sq[1][0]), sq[1][1]);
            float t2 = fmaxf(fmaxf(sq[1][2], sq[1][3]), sq[2][0]);
            float t3 = fmaxf(fmaxf(sq[2][1], sq[2][2]), sq[2][3]);
            float t4 = fmaxf(fmaxf(sq[3][0], sq[3][1]), sq[3][2]);
            float tl = fmaxf(fmaxf(t0, t1), sq[3][3]);
            tl = fmaxf(fmaxf(tl, t2), fmaxf(t3, t4));
            if (__any(tl > mrow[qt] + 8.0f)) {
                float t = fmaxf(tl, __shfl_xor(tl, 16));
                t = fmaxf(t, __shfl_xor(t, 32));
                const float newm = fmaxf(mrow[qt], t);
                const float sc = exp2f(mrow[qt] - newm);
                mrow[qt] = newm;
                lsacc[qt][0] *= sc; lsacc[qt][1] *= sc;
                lsacc[qt][2] *= sc; lsacc[qt][3] *= sc;
#pragma unroll
                for (int dt = 0; dt < 4; ++dt) {
                    ot[qt][dt][0] *= sc; ot[qt][dt][1] *= sc;
                    ot[qt][dt][2] *= sc; ot[qt][dt][3] *= sc;
                }
            }
            const float mq = mrow[qt];
#pragma unroll
            for (int ks = 0; ks < 4; ++ks) {
                pf[qt][ks] = pack4(exp2f(sq[ks][0] - mq), exp2f(sq[ks][1] - mq),
                                   exp2f(sq[ks][2] - mq), exp2f(sq[ks][3] - mq));
                lsacc[qt] = mfma16(ones, pf[qt][ks], lsacc[qt]);
            }
        }

        // ---- PV: out^T[d, q] += VT_tile x P ----
#pragma unroll
        for (int dt = 0; dt < 4; ++dt) {
            const int vrow = (dt * 16 + lr) * 64;
            bf16x8 v01 = *(const bf16x8*)&vl[vrow + vu0];
            bf16x8 v23 = *(const bf16x8*)&vl[vrow + vu1];
            bf16x4 vf0 = __builtin_shufflevector(v01, v01, 0, 1, 2, 3);
            bf16x4 vf1 = __builtin_shufflevector(v01, v01, 4, 5, 6, 7);
            bf16x4 vf2 = __builtin_shufflevector(v23, v23, 0, 1, 2, 3);
            bf16x4 vf3 = __builtin_shufflevector(v23, v23, 4, 5, 6, 7);
            ot[0][dt] = mfma16(vf0, pf[0][0], ot[0][dt]);
            ot[0][dt] = mfma16(vf1, pf[0][1], ot[0][dt]);
            ot[0][dt] = mfma16(vf2, pf[0][2], ot[0][dt]);
            ot[0][dt] = mfma16(vf3, pf[0][3], ot[0][dt]);
            ot[1][dt] = mfma16(vf0, pf[1][0], ot[1][dt]);
            ot[1][dt] = mfma16(vf1, pf[1][1], ot[1][dt]);
            ot[1][dt] = mfma16(vf2, pf[1][2], ot[1][dt]);
            ot[1][dt] = mfma16(vf3, pf[1][3], ot[1][dt]);
        }

        __syncthreads();
        cur ^= 1;
    }

    // ---- epilogue: normalize, LDS transpose, coalesced store ----
    const float inv0 = 1.0f / lsacc[0][0], inv1 = 1.0f / lsacc[1][0];
    u16* t_ = &kt[0][0] + wave * 2048;
#pragma unroll
    for (int qt = 0; qt < 2; ++qt) {
        const float inv = qt ? inv1 : inv0;
#pragma unroll
        for (int dt = 0; dt < 4; ++dt)
#pragma unroll
            for (int r = 0; r < 4; ++r)
                t_[(qt * 16 + lr) * 64 + dt * 16 + lg * 4 + r] = f2bf(ot[qt][dt][r] * inv);
    }
    __syncthreads();
    const int qq = lane >> 1, dseg = (lane & 1) * 32;
    u16* dst = AO + (size_t)(b * 2048 + q0 + qq) * 1024 + h * 64 + dseg;
    bf16x8 o_[4];
#pragma unroll
    for (int j = 0; j < 4; ++j) o_[j] = *(const bf16x8*)&t_[qq * 64 + dseg + j * 8];
#pragma unroll
    for (int j = 0; j < 4; ++j) *(bf16x8*)(dst + j * 8) = o_[j];
#undef STAGE
}

// ---------------- launcher ----------------
extern "C" void kernel_launch(void* const* d_in, const int* in_sizes, int n_in,
                              void* d_out, int out_size, void* d_ws, size_t ws_size,
                              hipStream_t stream) {
    const float* q_in = (const float*)d_in[0];
    const float* k_in = (const float*)d_in[1];
    const float* v_in = (const float*)d_in[2];
    const float* Wq = (const float*)d_in[3];
    const float* bq = (const float*)d_in[4];
    const float* Wk = (const float*)d_in[5];
    const float* bk = (const float*)d_in[6];
    const float* Wv = (const float*)d_in[7];
    const float* bv = (const float*)d_in[8];
    const float* Wo = (const float*)d_in[9];
    const float* bo = (const float*)d_in[10];

    const size_t MD = (size_t)8192 * 1024;
    const size_t DD = (size_t)1024 * 1024;
    u16* ws = (u16*)d_ws;
    u16* Xq = ws;
    u16* Xk = Xq + MD;
    u16* Xv = Xk + MD;
    u16* Wqb = Xv + MD;
    u16* Wkb = Wqb + DD;
    u16* Wvb = Wkb + DD;
    u16* Wob = Wvb + DD;
    u16* Qp = Wob + DD;
    u16* Kp = Qp + MD;
    u16* VTb = Kp + MD;
    u16* AO = VTb + MD;

    cvt_bf16<<<8192, 256, 0, stream>>>(q_in, Xq);
    cvt_bf16<<<8192, 256, 0, stream>>>(k_in, Xk);
    cvt_bf16<<<8192, 256, 0, stream>>>(v_in, Xv);
    cvt_bf16<<<1024, 256, 0, stream>>>(Wq, Wqb);
    cvt_bf16<<<1024, 256, 0, stream>>>(Wk, Wkb);
    cvt_bf16<<<1024, 256, 0, stream>>>(Wv, Wvb);
    cvt_bf16<<<1024, 256, 0, stream>>>(Wo, Wob);

    dim3 gg(8, 64);
    gemm_bt<1><<<gg, 256, 0, stream>>>(Xq, Wqb, bq, Qp, LOG2E_OVER8);
    gemm_bt<1><<<gg, 256, 0, stream>>>(Xk, Wkb, bk, Kp, 1.0f);
    gemm_bt<2><<<gg, 256, 0, stream>>>(Xv, Wvb, bv, VTb, 1.0f);

    attn_fwd<<<dim3(16, 64), 256, 0, stream>>>(Qp, Kp, VTb, AO);

    gemm_bt<0><<<gg, 256, 0, stream>>>(AO, Wob, bo, d_out, 1.0f);
}

// Round 5
// 270.071 us; speedup vs baseline: 3.0556x; 1.1204x over previous
//
#include <hip/hip_runtime.h>
#include <hip/hip_bf16.h>

typedef unsigned short u16;
typedef __attribute__((ext_vector_type(8))) short bf16x8;
typedef __attribute__((ext_vector_type(4))) short bf16x4;
typedef __attribute__((ext_vector_type(4))) float f32x4;
typedef __attribute__((ext_vector_type(2))) unsigned int u32x2;

#define LOG2E_OVER8 0.18033688011112043f

__device__ __forceinline__ float ex2(float x) {
#if __has_builtin(__builtin_amdgcn_exp2f)
    return __builtin_amdgcn_exp2f(x);
#else
    float r;
    asm volatile("v_exp_f32 %0, %1" : "=v"(r) : "v"(x));
    return r;
#endif
}

__device__ __forceinline__ u16 f2bf(float f) {
    unsigned u = __float_as_uint(f);
    u += 0x7FFFu + ((u >> 16) & 1u);   // RNE
    return (u16)(u >> 16);
}

__device__ __forceinline__ unsigned cvtpk_bf16(float a, float b) {
    float2 t; t.x = a; t.y = b;
    __hip_bfloat162 h = __float22bfloat162_rn(t);
    unsigned r;
    __builtin_memcpy(&r, &h, 4);
    return r;
}
__device__ __forceinline__ bf16x4 pack4(float a, float b, float c, float d) {
    u32x2 p; p[0] = cvtpk_bf16(a, b); p[1] = cvtpk_bf16(c, d);
    bf16x4 r;
    __builtin_memcpy(&r, &p, 8);
    return r;
}

__device__ __forceinline__ f32x4 mfma32(bf16x8 a, bf16x8 b, f32x4 c) {
    return __builtin_amdgcn_mfma_f32_16x16x32_bf16(a, b, c, 0, 0, 0);
}
__device__ __forceinline__ f32x4 mfma16(bf16x4 a, bf16x4 b, f32x4 c) {
    return __builtin_amdgcn_mfma_f32_16x16x16bf16_1k(a, b, c, 0, 0, 0);
}

__device__ __forceinline__ void gload16(const void* g, void* l) {
    __builtin_amdgcn_global_load_lds((const __attribute__((address_space(1))) unsigned int*)g,
                                     (__attribute__((address_space(3))) unsigned int*)l,
                                     16, 0, 0);
}

// ---------------- fp32 -> bf16 conversion (vectorized x4) ----------------
__global__ __launch_bounds__(256) void cvt_bf16(const float* __restrict__ in, u16* __restrict__ out) {
    size_t i = ((size_t)blockIdx.x * 256 + threadIdx.x) * 4;
    float4 v = *(const float4*)(in + i);
    u16 r0 = f2bf(v.x), r1 = f2bf(v.y), r2 = f2bf(v.z), r3 = f2bf(v.w);
    bf16x4 o; o[0] = (short)r0; o[1] = (short)r1; o[2] = (short)r2; o[3] = (short)r3;
    *(bf16x4*)(out + i) = o;
}

// ---------------- GEMM: C[m,n] = sum_k A[m,k] * Bt[n,k] + bias[n] ----------------
// MODE 0: fp32 out. MODE 1: bf16 out, value=(acc+bias)*scale.
// MODE 2: bf16 out in attn-V "LDS image" layout:
//   [b, h, kb(32)] tiles of 4096 elems; within tile, element for (k64, d):
//   u = ((k64>>2)&3)*2 + ((k64>>5)&1); j = ((k64>>4)&1)*4 + (k64&3);
//   pos = d*64 + ((u ^ (d&7))*8) + j.
template<int MODE>
__global__ __launch_bounds__(256) void gemm_bt(const u16* __restrict__ A, const u16* __restrict__ Bt,
                                               const float* __restrict__ bias, void* __restrict__ Cout,
                                               float scale) {
    constexpr int K = 1024, N = 1024;
    __shared__ u16 As[128 * 32];
    __shared__ u16 Bs[128 * 32];
    const int tid = threadIdx.x;
    const int lane = tid & 63, wid = tid >> 6;
    const int wr = wid >> 1, wc = wid & 1;
    const int lr = lane & 15, lg = lane >> 4;
    const int bm = blockIdx.y * 128, bn = blockIdx.x * 128;

    f32x4 acc[4][4];
    for (int i = 0; i < 4; i++)
        for (int j = 0; j < 4; j++) acc[i][j] = (f32x4){0.f, 0.f, 0.f, 0.f};

    const int c0 = tid, c1 = 256 + tid;
    const size_t a_off0 = (size_t)(bm + (c0 >> 2)) * K + (c0 & 3) * 8;
    const size_t a_off1 = (size_t)(bm + (c1 >> 2)) * K + (c1 & 3) * 8;
    const size_t b_off0 = (size_t)(bn + (c0 >> 2)) * K + (c0 & 3) * 8;
    const size_t b_off1 = (size_t)(bn + (c1 >> 2)) * K + (c1 & 3) * 8;

    for (int kt = 0; kt < K; kt += 32) {
        gload16(A + a_off0 + kt, &As[c0 * 8]);
        gload16(A + a_off1 + kt, &As[c1 * 8]);
        gload16(Bt + b_off0 + kt, &Bs[c0 * 8]);
        gload16(Bt + b_off1 + kt, &Bs[c1 * 8]);
        __syncthreads();
        bf16x8 aF[4], bF[4];
#pragma unroll
        for (int mi = 0; mi < 4; mi++) aF[mi] = *(const bf16x8*)&As[(wr * 64 + mi * 16 + lr) * 32 + lg * 8];
#pragma unroll
        for (int ni = 0; ni < 4; ni++) bF[ni] = *(const bf16x8*)&Bs[(wc * 64 + ni * 16 + lr) * 32 + lg * 8];
#pragma unroll
        for (int mi = 0; mi < 4; mi++)
#pragma unroll
            for (int ni = 0; ni < 4; ni++) acc[mi][ni] = mfma32(aF[mi], bF[ni], acc[mi][ni]);
        __syncthreads();
    }

#pragma unroll
    for (int ni = 0; ni < 4; ni++) {
        const int n = bn + wc * 64 + ni * 16 + lr;
        const float bv = bias[n];
#pragma unroll
        for (int mi = 0; mi < 4; mi++) {
            const int mbase = bm + wr * 64 + mi * 16 + lg * 4;
#pragma unroll
            for (int r = 0; r < 4; r++) {
                const int m = mbase + r;
                const float v = acc[mi][ni][r] + bv;
                if (MODE == 0) {
                    ((float*)Cout)[(size_t)m * N + n] = v;
                } else if (MODE == 1) {
                    ((u16*)Cout)[(size_t)m * N + n] = f2bf(v * scale);
                } else {
                    const int bq_ = m >> 11, kk = m & 2047, kb = kk >> 6, k64 = kk & 63;
                    const int hh = n >> 6, dd = n & 63;
                    const int u = (((k64 >> 2) & 3) << 1) | ((k64 >> 5) & 1);
                    const int jj = (((k64 >> 4) & 1) << 2) | (k64 & 3);
                    ((u16*)Cout)[((size_t)((bq_ * 16 + hh) * 32 + kb)) * 4096 +
                                 dd * 64 + ((u ^ (dd & 7)) << 3) + jj] = f2bf(v);
                }
            }
        }
    }
}

// ---------------- Flash attention v4 ----------------
// Qp, Kp: bf16 [B*S, 1024]; Qp pre-scaled by log2e/8. VT: bf16 image layout (above).
// Grid: (S/128, B*H), 4 waves/block; each wave owns 32 q rows (2 q-tiles of 16).
// K tile [64k][64d] XOR-swizzled via pre-swizzled source; V tile = linear image copy.
// Softmax: defer-max (THR=8, log2 domain), raw v_exp_f32, lsum via ones-MFMA.
__global__ __launch_bounds__(256) void attn_fwd(const u16* __restrict__ Qp, const u16* __restrict__ Kp,
                                                const u16* __restrict__ VTb, u16* __restrict__ AO) {
    __shared__ u16 kt[2][4096];
    __shared__ u16 vt[2][4096];
    const int tid = threadIdx.x;
    const int lane = tid & 63, wave = tid >> 6;
    const int lr = lane & 15, lg = lane >> 4;
    const int l7 = lr & 7;
    const int bh = blockIdx.y, b = bh >> 4, h = bh & 15;
    const int q0 = blockIdx.x * 128 + wave * 32;

    const u16* qbase = Qp + (size_t)(b * 2048 + q0) * 1024 + h * 64;
    bf16x8 qf[2][2];
#pragma unroll
    for (int qt = 0; qt < 2; qt++)
#pragma unroll
        for (int hf = 0; hf < 2; hf++)
            qf[qt][hf] = *(const bf16x8*)(qbase + (size_t)(qt * 16 + lr) * 1024 + hf * 32 + lg * 8);

    const int srow = tid >> 3;
    const int scol = (((tid & 7) ^ (srow & 7)) * 8);
    const u16* kg = Kp + (size_t)(b * 2048 + srow) * 1024 + h * 64 + scol;
    const u16* vg = VTb + (size_t)(b * 16 + h) * 32 * 4096 + tid * 8;
    const int ldst = tid * 8;

#define STAGE(buf, kb_)                                                       \
    do {                                                                      \
        gload16(kg + (size_t)(kb_) * 64 * 1024,        &kt[buf][ldst]);       \
        gload16(kg + (size_t)((kb_) * 64 + 32) * 1024, &kt[buf][2048 + ldst]);\
        gload16(vg + (size_t)(kb_) * 4096,             &vt[buf][ldst]);       \
        gload16(vg + (size_t)(kb_) * 4096 + 2048,      &vt[buf][2048 + ldst]);\
    } while (0)

    float mrow[2] = {-3.0e38f, -3.0e38f};
    f32x4 lsacc[2];
    f32x4 ot[2][4];
#pragma unroll
    for (int qt = 0; qt < 2; qt++) {
        lsacc[qt] = (f32x4){0.f, 0.f, 0.f, 0.f};
#pragma unroll
        for (int dt = 0; dt < 4; dt++) ot[qt][dt] = (f32x4){0.f, 0.f, 0.f, 0.f};
    }

    bf16x4 ones;
    ones[0] = ones[1] = ones[2] = ones[3] = (short)0x3F80;

    STAGE(0, 0);
    __syncthreads();
    int cur = 0;

    const f32x4 zero = (f32x4){0.f, 0.f, 0.f, 0.f};
    const int ku0 = (lg ^ l7) * 8;
    const int ku1 = ((4 + lg) ^ l7) * 8;
    const int vu0 = ((lg * 2) ^ l7) * 8;
    const int vu1 = ((lg * 2 + 1) ^ l7) * 8;

    for (int it = 0; it < 32; ++it) {
        if (it < 31) STAGE(cur ^ 1, it + 1);

        const u16* kl = &kt[cur][0];
        const u16* vl = &vt[cur][0];

        // ---- QK^T (swapped): s[qt][ks] = K_tile x Q -> D[k_row, q_col] ----
        f32x4 s[2][4];
        __builtin_amdgcn_s_setprio(1);
#pragma unroll
        for (int ks = 0; ks < 4; ++ks) {
            const int rbase = (ks * 16 + lr) * 64;
            bf16x8 kf0 = *(const bf16x8*)&kl[rbase + ku0];
            bf16x8 kf1 = *(const bf16x8*)&kl[rbase + ku1];
            s[0][ks] = mfma32(kf0, qf[0][0], zero);
            s[0][ks] = mfma32(kf1, qf[0][1], s[0][ks]);
            s[1][ks] = mfma32(kf0, qf[1][0], zero);
            s[1][ks] = mfma32(kf1, qf[1][1], s[1][ks]);
        }
        __builtin_amdgcn_s_setprio(0);

        // ---- online softmax, defer-max, psum via ones-MFMA ----
        bf16x4 pf[2][4];
#pragma unroll
        for (int qt = 0; qt < 2; ++qt) {
            const f32x4* sq = s[qt];
            float t0 = fmaxf(fmaxf(sq[0][0], sq[0][1]), sq[0][2]);
            float t1 = fmaxf(fmaxf(sq[0][3], sq[1][0]), sq[1][1]);
            float t2 = fmaxf(fmaxf(sq[1][2], sq[1][3]), sq[2][0]);
            float t3 = fmaxf(fmaxf(sq[2][1], sq[2][2]), sq[2][3]);
            float t4 = fmaxf(fmaxf(sq[3][0], sq[3][1]), sq[3][2]);
            float tl = fmaxf(fmaxf(t0, t1), sq[3][3]);
            tl = fmaxf(fmaxf(tl, t2), fmaxf(t3, t4));
            if (__any(tl > mrow[qt] + 8.0f)) {
                float t = fmaxf(tl, __shfl_xor(tl, 16));
                t = fmaxf(t, __shfl_xor(t, 32));
                const float newm = fmaxf(mrow[qt], t);
                const float sc = ex2(mrow[qt] - newm);
                mrow[qt] = newm;
                lsacc[qt][0] *= sc; lsacc[qt][1] *= sc;
                lsacc[qt][2] *= sc; lsacc[qt][3] *= sc;
#pragma unroll
                for (int dt = 0; dt < 4; ++dt) {
                    ot[qt][dt][0] *= sc; ot[qt][dt][1] *= sc;
                    ot[qt][dt][2] *= sc; ot[qt][dt][3] *= sc;
                }
            }
            const float mq = mrow[qt];
#pragma unroll
            for (int ks = 0; ks < 4; ++ks) {
                pf[qt][ks] = pack4(ex2(sq[ks][0] - mq), ex2(sq[ks][1] - mq),
                                   ex2(sq[ks][2] - mq), ex2(sq[ks][3] - mq));
                lsacc[qt] = mfma16(ones, pf[qt][ks], lsacc[qt]);
            }
        }

        // ---- PV: out^T[d, q] += VT_tile x P ----
        __builtin_amdgcn_s_setprio(1);
#pragma unroll
        for (int dt = 0; dt < 4; ++dt) {
            const int vrow = (dt * 16 + lr) * 64;
            bf16x8 v01 = *(const bf16x8*)&vl[vrow + vu0];
            bf16x8 v23 = *(const bf16x8*)&vl[vrow + vu1];
            bf16x4 vf0 = __builtin_shufflevector(v01, v01, 0, 1, 2, 3);
            bf16x4 vf1 = __builtin_shufflevector(v01, v01, 4, 5, 6, 7);
            bf16x4 vf2 = __builtin_shufflevector(v23, v23, 0, 1, 2, 3);
            bf16x4 vf3 = __builtin_shufflevector(v23, v23, 4, 5, 6, 7);
            ot[0][dt] = mfma16(vf0, pf[0][0], ot[0][dt]);
            ot[0][dt] = mfma16(vf1, pf[0][1], ot[0][dt]);
            ot[0][dt] = mfma16(vf2, pf[0][2], ot[0][dt]);
            ot[0][dt] = mfma16(vf3, pf[0][3], ot[0][dt]);
            ot[1][dt] = mfma16(vf0, pf[1][0], ot[1][dt]);
            ot[1][dt] = mfma16(vf1, pf[1][1], ot[1][dt]);
            ot[1][dt] = mfma16(vf2, pf[1][2], ot[1][dt]);
            ot[1][dt] = mfma16(vf3, pf[1][3], ot[1][dt]);
        }
        __builtin_amdgcn_s_setprio(0);

        __syncthreads();
        cur ^= 1;
    }

    // ---- epilogue: normalize, LDS transpose, coalesced store ----
    const float inv0 = 1.0f / lsacc[0][0], inv1 = 1.0f / lsacc[1][0];
    u16* t_ = &kt[0][0] + wave * 2048;
#pragma unroll
    for (int qt = 0; qt < 2; ++qt) {
        const float inv = qt ? inv1 : inv0;
#pragma unroll
        for (int dt = 0; dt < 4; ++dt)
#pragma unroll
            for (int r = 0; r < 4; ++r)
                t_[(qt * 16 + lr) * 64 + dt * 16 + lg * 4 + r] = f2bf(ot[qt][dt][r] * inv);
    }
    __syncthreads();
    const int qq = lane >> 1, dseg = (lane & 1) * 32;
    u16* dst = AO + (size_t)(b * 2048 + q0 + qq) * 1024 + h * 64 + dseg;
    bf16x8 o_[4];
#pragma unroll
    for (int j = 0; j < 4; ++j) o_[j] = *(const bf16x8*)&t_[qq * 64 + dseg + j * 8];
#pragma unroll
    for (int j = 0; j < 4; ++j) *(bf16x8*)(dst + j * 8) = o_[j];
#undef STAGE
}

// ---------------- launcher ----------------
extern "C" void kernel_launch(void* const* d_in, const int* in_sizes, int n_in,
                              void* d_out, int out_size, void* d_ws, size_t ws_size,
                              hipStream_t stream) {
    const float* q_in = (const float*)d_in[0];
    const float* k_in = (const float*)d_in[1];
    const float* v_in = (const float*)d_in[2];
    const float* Wq = (const float*)d_in[3];
    const float* bq = (const float*)d_in[4];
    const float* Wk = (const float*)d_in[5];
    const float* bk = (const float*)d_in[6];
    const float* Wv = (const float*)d_in[7];
    const float* bv = (const float*)d_in[8];
    const float* Wo = (const float*)d_in[9];
    const float* bo = (const float*)d_in[10];

    const size_t MD = (size_t)8192 * 1024;
    const size_t DD = (size_t)1024 * 1024;
    u16* ws = (u16*)d_ws;
    u16* Xq = ws;
    u16* Xk = Xq + MD;
    u16* Xv = Xk + MD;
    u16* Wqb = Xv + MD;
    u16* Wkb = Wqb + DD;
    u16* Wvb = Wkb + DD;
    u16* Wob = Wvb + DD;
    u16* Qp = Wob + DD;
    u16* Kp = Qp + MD;
    u16* VTb = Kp + MD;
    u16* AO = VTb + MD;

    cvt_bf16<<<8192, 256, 0, stream>>>(q_in, Xq);
    cvt_bf16<<<8192, 256, 0, stream>>>(k_in, Xk);
    cvt_bf16<<<8192, 256, 0, stream>>>(v_in, Xv);
    cvt_bf16<<<1024, 256, 0, stream>>>(Wq, Wqb);
    cvt_bf16<<<1024, 256, 0, stream>>>(Wk, Wkb);
    cvt_bf16<<<1024, 256, 0, stream>>>(Wv, Wvb);
    cvt_bf16<<<1024, 256, 0, stream>>>(Wo, Wob);

    dim3 gg(8, 64);
    gemm_bt<1><<<gg, 256, 0, stream>>>(Xq, Wqb, bq, Qp, LOG2E_OVER8);
    gemm_bt<1><<<gg, 256, 0, stream>>>(Xk, Wkb, bk, Kp, 1.0f);
    gemm_bt<2><<<gg, 256, 0, stream>>>(Xv, Wvb, bv, VTb, 1.0f);

    attn_fwd<<<dim3(16, 64), 256, 0, stream>>>(Qp, Kp, VTb, AO);

    gemm_bt<0><<<gg, 256, 0, stream>>>(AO, Wob, bo, d_out, 1.0f);
}

// Round 8
// 253.401 us; speedup vs baseline: 3.2566x; 1.0658x over previous
//
#include <hip/hip_runtime.h>
#include <hip/hip_bf16.h>

typedef unsigned short u16;
typedef __attribute__((ext_vector_type(8))) short bf16x8;
typedef __attribute__((ext_vector_type(4))) short bf16x4;
typedef __attribute__((ext_vector_type(4))) float f32x4;

#define LOG2E_OVER8 0.18033688011112043f

__device__ __forceinline__ float ex2(float x) {
#if __has_builtin(__builtin_amdgcn_exp2f)
    return __builtin_amdgcn_exp2f(x);
#else
    float r;
    asm volatile("v_exp_f32 %0, %1" : "=v"(r) : "v"(x));
    return r;
#endif
}

__device__ __forceinline__ u16 f2bf(float f) {
    unsigned u = __float_as_uint(f);
    u += 0x7FFFu + ((u >> 16) & 1u);   // RNE
    return (u16)(u >> 16);
}

// RTZ packed f32->bf16 pair via one v_perm_b32: D = {hi.b3,hi.b2, lo.b3,lo.b2}.
// Safe for P in [0,256]; truncation cancels in the PV/lsum ratio since the SAME
// bf16 P feeds both. (v_cvt_pk_bf16_f32 asm produced NaNs -> suspected stale
// high-half; v_perm is unambiguous.)
__device__ __forceinline__ unsigned pk_rtz(float lo, float hi) {
    return __builtin_amdgcn_perm(__float_as_uint(hi), __float_as_uint(lo), 0x07060302u);
}
__device__ __forceinline__ bf16x4 pack4(float a, float b, float c, float d) {
    unsigned p[2];
    p[0] = pk_rtz(a, b);
    p[1] = pk_rtz(c, d);
    bf16x4 r;
    __builtin_memcpy(&r, p, 8);
    return r;
}

__device__ __forceinline__ f32x4 mfma32(bf16x8 a, bf16x8 b, f32x4 c) {
    return __builtin_amdgcn_mfma_f32_16x16x32_bf16(a, b, c, 0, 0, 0);
}
__device__ __forceinline__ f32x4 mfma16(bf16x4 a, bf16x4 b, f32x4 c) {
    return __builtin_amdgcn_mfma_f32_16x16x16bf16_1k(a, b, c, 0, 0, 0);
}

__device__ __forceinline__ void gload16(const void* g, void* l) {
    __builtin_amdgcn_global_load_lds((const __attribute__((address_space(1))) unsigned int*)g,
                                     (__attribute__((address_space(3))) unsigned int*)l,
                                     16, 0, 0);
}

// ---------------- fp32 -> bf16 conversion (fused, vectorized x4) ----------------
__global__ __launch_bounds__(256) void cvt_x3(const float* __restrict__ a, const float* __restrict__ b,
                                              const float* __restrict__ c, u16* __restrict__ out) {
    const float* src = (blockIdx.y == 0) ? a : (blockIdx.y == 1) ? b : c;
    size_t i = ((size_t)blockIdx.x * 256 + threadIdx.x) * 4;
    float4 v = *(const float4*)(src + i);
    bf16x4 o;
    o[0] = (short)f2bf(v.x); o[1] = (short)f2bf(v.y);
    o[2] = (short)f2bf(v.z); o[3] = (short)f2bf(v.w);
    *(bf16x4*)(out + (size_t)blockIdx.y * (8192ull * 1024) + i) = o;
}
__global__ __launch_bounds__(256) void cvt_w4(const float* __restrict__ a, const float* __restrict__ b,
                                              const float* __restrict__ c, const float* __restrict__ d,
                                              u16* __restrict__ out) {
    const float* src = (blockIdx.y == 0) ? a : (blockIdx.y == 1) ? b : (blockIdx.y == 2) ? c : d;
    size_t i = ((size_t)blockIdx.x * 256 + threadIdx.x) * 4;
    float4 v = *(const float4*)(src + i);
    bf16x4 o;
    o[0] = (short)f2bf(v.x); o[1] = (short)f2bf(v.y);
    o[2] = (short)f2bf(v.z); o[3] = (short)f2bf(v.w);
    *(bf16x4*)(out + (size_t)blockIdx.y * (1024ull * 1024) + i) = o;
}

// ---------------- GEMM: C[m,n] = sum_k A[m,k] * Bt[n,k] + bias[n] ----------------
// MODE 0: fp32 out. MODE 1: bf16 out, value=(acc+bias)*scale.
// MODE 2: bf16 out in attn-V "LDS image" layout (see attn comments).
template<int MODE>
__global__ __launch_bounds__(256) void gemm_bt(const u16* __restrict__ A, const u16* __restrict__ Bt,
                                               const float* __restrict__ bias, void* __restrict__ Cout,
                                               float scale) {
    constexpr int K = 1024, N = 1024;
    __shared__ u16 As[128 * 32];
    __shared__ u16 Bs[128 * 32];
    const int tid = threadIdx.x;
    const int lane = tid & 63, wid = tid >> 6;
    const int wr = wid >> 1, wc = wid & 1;
    const int lr = lane & 15, lg = lane >> 4;
    const int bm = blockIdx.y * 128, bn = blockIdx.x * 128;

    f32x4 acc[4][4];
    for (int i = 0; i < 4; i++)
        for (int j = 0; j < 4; j++) acc[i][j] = (f32x4){0.f, 0.f, 0.f, 0.f};

    const int c0 = tid, c1 = 256 + tid;
    const size_t a_off0 = (size_t)(bm + (c0 >> 2)) * K + (c0 & 3) * 8;
    const size_t a_off1 = (size_t)(bm + (c1 >> 2)) * K + (c1 & 3) * 8;
    const size_t b_off0 = (size_t)(bn + (c0 >> 2)) * K + (c0 & 3) * 8;
    const size_t b_off1 = (size_t)(bn + (c1 >> 2)) * K + (c1 & 3) * 8;

    for (int kt = 0; kt < K; kt += 32) {
        gload16(A + a_off0 + kt, &As[c0 * 8]);
        gload16(A + a_off1 + kt, &As[c1 * 8]);
        gload16(Bt + b_off0 + kt, &Bs[c0 * 8]);
        gload16(Bt + b_off1 + kt, &Bs[c1 * 8]);
        __syncthreads();
        bf16x8 aF[4], bF[4];
#pragma unroll
        for (int mi = 0; mi < 4; mi++) aF[mi] = *(const bf16x8*)&As[(wr * 64 + mi * 16 + lr) * 32 + lg * 8];
#pragma unroll
        for (int ni = 0; ni < 4; ni++) bF[ni] = *(const bf16x8*)&Bs[(wc * 64 + ni * 16 + lr) * 32 + lg * 8];
#pragma unroll
        for (int mi = 0; mi < 4; mi++)
#pragma unroll
            for (int ni = 0; ni < 4; ni++) acc[mi][ni] = mfma32(aF[mi], bF[ni], acc[mi][ni]);
        __syncthreads();
    }

#pragma unroll
    for (int ni = 0; ni < 4; ni++) {
        const int n = bn + wc * 64 + ni * 16 + lr;
        const float bv = bias[n];
#pragma unroll
        for (int mi = 0; mi < 4; mi++) {
            const int mbase = bm + wr * 64 + mi * 16 + lg * 4;
#pragma unroll
            for (int r = 0; r < 4; r++) {
                const int m = mbase + r;
                const float v = acc[mi][ni][r] + bv;
                if (MODE == 0) {
                    ((float*)Cout)[(size_t)m * N + n] = v;
                } else if (MODE == 1) {
                    ((u16*)Cout)[(size_t)m * N + n] = f2bf(v * scale);
                } else {
                    const int bq_ = m >> 11, kk = m & 2047, kb = kk >> 6, k64 = kk & 63;
                    const int hh = n >> 6, dd = n & 63;
                    const int u = (((k64 >> 2) & 3) << 1) | ((k64 >> 5) & 1);
                    const int jj = (((k64 >> 4) & 1) << 2) | (k64 & 3);
                    ((u16*)Cout)[((size_t)((bq_ * 16 + hh) * 32 + kb)) * 4096 +
                                 dd * 64 + ((u ^ (dd & 7)) << 3) + jj] = f2bf(v);
                }
            }
        }
    }
}

// ---------------- Flash attention v7 (v4 softmax semantics + perm-RTZ pack) ----------------
// Qp, Kp: bf16 [B*S, 1024]; Qp pre-scaled by log2e/8. VT: bf16 image layout.
// Grid: (S/128, B*H), 4 waves/block; each wave owns 32 q rows (2 q-tiles of 16).
// Defer-rescale (T13, THR=8 in log2 domain), explicit running max (init -3e38).
__global__ __launch_bounds__(256) void attn_fwd(const u16* __restrict__ Qp, const u16* __restrict__ Kp,
                                                const u16* __restrict__ VTb, u16* __restrict__ AO) {
    __shared__ u16 kt[2][4096];
    __shared__ u16 vt[2][4096];
    const int tid = threadIdx.x;
    const int lane = tid & 63, wave = tid >> 6;
    const int lr = lane & 15, lg = lane >> 4;
    const int l7 = lr & 7;
    const int bh = blockIdx.y, b = bh >> 4, h = bh & 15;
    const int q0 = blockIdx.x * 128 + wave * 32;

    const u16* qbase = Qp + (size_t)(b * 2048 + q0) * 1024 + h * 64;
    bf16x8 qf[2][2];
#pragma unroll
    for (int qt = 0; qt < 2; qt++)
#pragma unroll
        for (int hf = 0; hf < 2; hf++)
            qf[qt][hf] = *(const bf16x8*)(qbase + (size_t)(qt * 16 + lr) * 1024 + hf * 32 + lg * 8);

    const int srow = tid >> 3;
    const int scol = (((tid & 7) ^ (srow & 7)) * 8);
    const u16* kg = Kp + (size_t)(b * 2048 + srow) * 1024 + h * 64 + scol;
    const u16* vg = VTb + (size_t)(b * 16 + h) * 32 * 4096 + tid * 8;
    const int ldst = tid * 8;

#define STAGE(buf, kb_)                                                       \
    do {                                                                      \
        gload16(kg + (size_t)(kb_) * 64 * 1024,        &kt[buf][ldst]);       \
        gload16(kg + (size_t)((kb_) * 64 + 32) * 1024, &kt[buf][2048 + ldst]);\
        gload16(vg + (size_t)(kb_) * 4096,             &vt[buf][ldst]);       \
        gload16(vg + (size_t)(kb_) * 4096 + 2048,      &vt[buf][2048 + ldst]);\
    } while (0)

    float mrow[2] = {-3.0e38f, -3.0e38f};
    f32x4 lsacc[2];
    f32x4 ot[2][4];
#pragma unroll
    for (int qt = 0; qt < 2; qt++) {
        lsacc[qt] = (f32x4){0.f, 0.f, 0.f, 0.f};
#pragma unroll
        for (int dt = 0; dt < 4; dt++) ot[qt][dt] = (f32x4){0.f, 0.f, 0.f, 0.f};
    }

    bf16x4 ones;
    ones[0] = ones[1] = ones[2] = ones[3] = (short)0x3F80;

    STAGE(0, 0);
    __syncthreads();
    int cur = 0;

    const f32x4 zero = (f32x4){0.f, 0.f, 0.f, 0.f};
    const int ku0 = (lg ^ l7) * 8;
    const int ku1 = ((4 + lg) ^ l7) * 8;
    const int vu0 = ((lg * 2) ^ l7) * 8;
    const int vu1 = ((lg * 2 + 1) ^ l7) * 8;

    for (int it = 0; it < 32; ++it) {
        if (it < 31) STAGE(cur ^ 1, it + 1);

        const u16* kl = &kt[cur][0];
        const u16* vl = &vt[cur][0];

        // ---- QK^T (swapped): s[qt][ks] = K_tile x Q -> D[k_row, q_col] ----
        f32x4 s[2][4];
        __builtin_amdgcn_s_setprio(1);
#pragma unroll
        for (int ks = 0; ks < 4; ++ks) {
            const int rbase = (ks * 16 + lr) * 64;
            bf16x8 kf0 = *(const bf16x8*)&kl[rbase + ku0];
            bf16x8 kf1 = *(const bf16x8*)&kl[rbase + ku1];
            s[0][ks] = mfma32(kf0, qf[0][0], zero);
            s[0][ks] = mfma32(kf1, qf[0][1], s[0][ks]);
            s[1][ks] = mfma32(kf0, qf[1][0], zero);
            s[1][ks] = mfma32(kf1, qf[1][1], s[1][ks]);
        }
        __builtin_amdgcn_s_setprio(0);

        // ---- online softmax: defer-rescale (THR=8), exp2, lsum via ones-MFMA ----
        bf16x4 pf[2][4];
#pragma unroll
        for (int qt = 0; qt < 2; ++qt) {
            const f32x4* sq = s[qt];
            float t0 = fmaxf(fmaxf(sq[0][0], sq[0][1]), sq[0][2]);
            float t1 = fmaxf(fmaxf(sq[0][3], sq[1][0]), sq[1][1]);
            float t2 = fmaxf(fmaxf(sq[1][2], sq[1][3]), sq[2][0]);
            float t3 = fmaxf(fmaxf(sq[2][1], sq[2][2]), sq[2][3]);
            float t4 = fmaxf(fmaxf(sq[3][0], sq[3][1]), sq[3][2]);
            float tl = fmaxf(fmaxf(t0, t1), sq[3][3]);
            tl = fmaxf(fmaxf(tl, t2), fmaxf(t3, t4));
            if (__any(tl > mrow[qt] + 8.0f)) {
                float t = fmaxf(tl, __shfl_xor(tl, 16));
                t = fmaxf(t, __shfl_xor(t, 32));
                const float newm = fmaxf(mrow[qt], t);
                const float sc = ex2(mrow[qt] - newm);
                mrow[qt] = newm;
                lsacc[qt][0] *= sc; lsacc[qt][1] *= sc;
                lsacc[qt][2] *= sc; lsacc[qt][3] *= sc;
#pragma unroll
                for (int dt = 0; dt < 4; ++dt) {
                    ot[qt][dt][0] *= sc; ot[qt][dt][1] *= sc;
                    ot[qt][dt][2] *= sc; ot[qt][dt][3] *= sc;
                }
            }
            const float mq = mrow[qt];
#pragma unroll
            for (int ks = 0; ks < 4; ++ks) {
                pf[qt][ks] = pack4(ex2(sq[ks][0] - mq), ex2(sq[ks][1] - mq),
                                   ex2(sq[ks][2] - mq), ex2(sq[ks][3] - mq));
                lsacc[qt] = mfma16(ones, pf[qt][ks], lsacc[qt]);
            }
        }

        // ---- PV: out^T[d, q] += VT_tile x P ----
        __builtin_amdgcn_s_setprio(1);
#pragma unroll
        for (int dt = 0; dt < 4; ++dt) {
            const int vrow = (dt * 16 + lr) * 64;
            bf16x8 v01 = *(const bf16x8*)&vl[vrow + vu0];
            bf16x8 v23 = *(const bf16x8*)&vl[vrow + vu1];
            bf16x4 vf0 = __builtin_shufflevector(v01, v01, 0, 1, 2, 3);
            bf16x4 vf1 = __builtin_shufflevector(v01, v01, 4, 5, 6, 7);
            bf16x4 vf2 = __builtin_shufflevector(v23, v23, 0, 1, 2, 3);
            bf16x4 vf3 = __builtin_shufflevector(v23, v23, 4, 5, 6, 7);
            ot[0][dt] = mfma16(vf0, pf[0][0], ot[0][dt]);
            ot[0][dt] = mfma16(vf1, pf[0][1], ot[0][dt]);
            ot[0][dt] = mfma16(vf2, pf[0][2], ot[0][dt]);
            ot[0][dt] = mfma16(vf3, pf[0][3], ot[0][dt]);
            ot[1][dt] = mfma16(vf0, pf[1][0], ot[1][dt]);
            ot[1][dt] = mfma16(vf1, pf[1][1], ot[1][dt]);
            ot[1][dt] = mfma16(vf2, pf[1][2], ot[1][dt]);
            ot[1][dt] = mfma16(vf3, pf[1][3], ot[1][dt]);
        }
        __builtin_amdgcn_s_setprio(0);

        __syncthreads();
        cur ^= 1;
    }

    // ---- epilogue: normalize, LDS transpose, coalesced store ----
    const float inv0 = 1.0f / lsacc[0][0], inv1 = 1.0f / lsacc[1][0];
    u16* t_ = &kt[0][0] + wave * 2048;
#pragma unroll
    for (int qt = 0; qt < 2; ++qt) {
        const float inv = qt ? inv1 : inv0;
#pragma unroll
        for (int dt = 0; dt < 4; ++dt)
#pragma unroll
            for (int r = 0; r < 4; ++r)
                t_[(qt * 16 + lr) * 64 + dt * 16 + lg * 4 + r] = f2bf(ot[qt][dt][r] * inv);
    }
    __syncthreads();
    const int qq = lane >> 1, dseg = (lane & 1) * 32;
    u16* dst = AO + (size_t)(b * 2048 + q0 + qq) * 1024 + h * 64 + dseg;
    bf16x8 o_[4];
#pragma unroll
    for (int j = 0; j < 4; ++j) o_[j] = *(const bf16x8*)&t_[qq * 64 + dseg + j * 8];
#pragma unroll
    for (int j = 0; j < 4; ++j) *(bf16x8*)(dst + j * 8) = o_[j];
#undef STAGE
}

// ---------------- launcher ----------------
extern "C" void kernel_launch(void* const* d_in, const int* in_sizes, int n_in,
                              void* d_out, int out_size, void* d_ws, size_t ws_size,
                              hipStream_t stream) {
    const float* q_in = (const float*)d_in[0];
    const float* k_in = (const float*)d_in[1];
    const float* v_in = (const float*)d_in[2];
    const float* Wq = (const float*)d_in[3];
    const float* bq = (const float*)d_in[4];
    const float* Wk = (const float*)d_in[5];
    const float* bk = (const float*)d_in[6];
    const float* Wv = (const float*)d_in[7];
    const float* bv = (const float*)d_in[8];
    const float* Wo = (const float*)d_in[9];
    const float* bo = (const float*)d_in[10];

    const size_t MD = (size_t)8192 * 1024;
    const size_t DD = (size_t)1024 * 1024;
    u16* ws = (u16*)d_ws;
    u16* Xq = ws;                 // 3 contiguous activation buffers
    u16* Xk = Xq + MD;
    u16* Xv = Xk + MD;
    u16* Wqb = Xq + 3 * MD;       // 4 contiguous weight buffers
    u16* Wkb = Wqb + DD;
    u16* Wvb = Wkb + DD;
    u16* Wob = Wvb + DD;
    u16* Qp = Wqb + 4 * DD;
    u16* Kp = Qp + MD;
    u16* VTb = Kp + MD;
    u16* AO = VTb + MD;

    cvt_x3<<<dim3(8192, 3), 256, 0, stream>>>(q_in, k_in, v_in, Xq);
    cvt_w4<<<dim3(1024, 4), 256, 0, stream>>>(Wq, Wk, Wv, Wo, Wqb);

    dim3 gg(8, 64);
    gemm_bt<1><<<gg, 256, 0, stream>>>(Xq, Wqb, bq, Qp, LOG2E_OVER8);
    gemm_bt<1><<<gg, 256, 0, stream>>>(Xk, Wkb, bk, Kp, 1.0f);
    gemm_bt<2><<<gg, 256, 0, stream>>>(Xv, Wvb, bv, VTb, 1.0f);

    attn_fwd<<<dim3(16, 64), 256, 0, stream>>>(Qp, Kp, VTb, AO);

    gemm_bt<0><<<gg, 256, 0, stream>>>(AO, Wob, bo, d_out, 1.0f);
}